// Round 7
// baseline (140.297 us; speedup 1.0000x reference)
//
#include <hip/hip_runtime.h>
#include <hip/hip_cooperative_groups.h>

namespace cg = cooperative_groups;

typedef float f32x4 __attribute__((ext_vector_type(4)));

// out[b][v][p][i][s] = shell[s]*sh[i] / norm[b][l(i)][s]
// B=8 V=2048 P=32 I=16 S=4, monoms=20

__device__ __forceinline__ void compute_monoms(float nx, float ny, float nz, float* m) {
    float zp2 = nz*nz, zp3 = zp2*nz;
    float yp2 = ny*ny, yp3 = yp2*ny;
    float xp2 = nx*nx, xp3 = xp2*nx;
    m[0]=1.0f;  m[1]=nz;       m[2]=zp2;      m[3]=zp3;
    m[4]=ny;    m[5]=ny*nz;    m[6]=ny*zp2;
    m[7]=yp2;   m[8]=yp2*nz;   m[9]=yp3;
    m[10]=nx;   m[11]=nx*nz;   m[12]=nx*zp2;
    m[13]=nx*ny; m[14]=nx*ny*nz; m[15]=nx*yp2;
    m[16]=xp2;  m[17]=xp2*nz;  m[18]=xp2*ny;
    m[19]=xp3;
}

__device__ __forceinline__ void compute_shells(float dist, float* sl) {
    const float B1 = 32.0f/3.0f, B2 = 64.0f/3.0f, B3 = 32.0f;
    const float C1 = -16.0f/9.0f, C2 = -64.0f/9.0f, C3 = -16.0f;
    float nd2 = -16.0f * dist * dist;
    sl[0] = __expf(nd2);
    sl[1] = __expf(fmaf(B1, dist, nd2 + C1));
    sl[2] = __expf(fmaf(B2, dist, nd2 + C2));
    sl[3] = __expf(fmaf(B3, dist, nd2 + C3));
    float den = sl[0] + sl[1] + sl[2] + sl[3];
    float r = 1.0f / fmaxf(den, 1e-6f);
    float mask = (dist <= 1.0f) ? r : 0.0f;
#pragma unroll
    for (int s = 0; s < 4; ++s) sl[s] *= mask;
}

// ============ Single cooperative kernel: 512 blocks x 256 threads (2/CU) ============
// Phase 1: 32 units/block (4 iters of the 8-unit LDS pipeline) -> partials[blk][16]
// grid.sync -> Phase 2: 128 blocks reduce 64 rows each -> rcp_ws[128] -> grid.sync
// Phase 3: 1024 points/block (32 iters), Y rows + rcp hoisted, nt stores.
__global__ __launch_bounds__(256, 2) void sh_fused(const float* __restrict__ patches,
                                                   const float* __restrict__ Y,
                                                   float* __restrict__ partials,
                                                   float* __restrict__ rcp_ws,
                                                   f32x4* __restrict__ out) {
    __shared__ float sh2_lds[8][32][17];
    __shared__ float shl2_lds[8][32][5];
    __shared__ float l2_lds[8][16][4];
    __shared__ float red[8][16];
    __shared__ float rred[64];
    __shared__ float rcp_lds[16];

    const int tid  = threadIdx.x;
    const int blk  = blockIdx.x;
    const int wv   = tid >> 6;
    const int lane = tid & 63;
    const int half = lane >> 5;
    const int p    = lane & 31;
    const int u    = wv*2 + half;            // local unit 0..7

    // ================= Phase 1 =================
    float bsum = 0.f;
#pragma unroll 1
    for (int it = 0; it < 4; ++it) {
        const int unit = blk*32 + it*8 + u;  // 64 blocks per batch; all units same b
        const float* pp = patches + ((size_t)unit*32 + p)*3;
        float x = pp[0], y = pp[1], z = pp[2];
        float dist = sqrtf(x*x + y*y + z*z);
        float inv  = 1.0f / fmaxf(dist, 1e-6f);
        float nx = -x*inv, ny = -y*inv, nz = -z*inv;
        float m[20];
        compute_monoms(nx, ny, nz, m);
#pragma unroll
        for (int i = 0; i < 16; ++i) {
            float acc = 0.f;
#pragma unroll
            for (int j = 0; j < 20; ++j)
                acc = fmaf(Y[i*20 + j], m[j], acc);   // uniform -> s_load
            sh2_lds[u][p][i] = acc * acc;
        }
        float sl[4];
        compute_shells(dist, sl);
#pragma unroll
        for (int s = 0; s < 4; ++s) shl2_lds[u][p][s] = sl[s]*sl[s];
        __syncthreads();

        const int ri = lane >> 2, rs = lane & 3;
        const int u0 = wv*2, u1 = wv*2 + 1;
        float a0 = 0.f, a1 = 0.f;
#pragma unroll
        for (int q = 0; q < 32; ++q) {
            a0 = fmaf(sh2_lds[u0][q][ri], shl2_lds[u0][q][rs], a0);
            a1 = fmaf(sh2_lds[u1][q][ri], shl2_lds[u1][q][rs], a1);
        }
        l2_lds[u0][ri][rs] = a0;
        l2_lds[u1][ri][rs] = a1;
        __syncthreads();

        if (lane < 32) {
            const int h2 = lane >> 4;
            const int c  = lane & 15;        // c = l*4 + s
            const int l  = c >> 2, s = c & 3;
            const int uu = wv*2 + h2;
            const int start = l*l, cnt = 2*l + 1;
            float acc = 0.f;
            for (int t = 0; t < cnt; ++t) acc += l2_lds[uu][start + t][s];
            red[uu][c] = sqrtf(acc);
        }
        __syncthreads();
        if (tid < 16) {
            float s2 = 0.f;
#pragma unroll
            for (int uu = 0; uu < 8; ++uu) s2 += red[uu][tid];
            bsum += s2;
        }
        __syncthreads();
    }
    if (tid < 16) partials[blk*16 + tid] = bsum;

    cg::this_grid().sync();

    // ================= Phase 2 (blocks 0..127): rcp_ws[b*16+c] =================
    if (blk < 128) {
        const int b = blk >> 4, c = blk & 15;
        if (tid < 64) rred[tid] = partials[(b*64 + tid)*16 + c];
        __syncthreads();
        if (tid < 32) rred[tid] += rred[tid + 32];
        __syncthreads();
        if (tid < 16) rred[tid] += rred[tid + 16];
        __syncthreads();
        if (tid < 8)  rred[tid] += rred[tid + 8];
        __syncthreads();
        if (tid < 4)  rred[tid] += rred[tid + 4];
        __syncthreads();
        if (tid < 2)  rred[tid] += rred[tid + 2];
        __syncthreads();
        if (tid == 0) {
            float meanv = (rred[0] + rred[1]) * (1.0f/2048.0f);
            rcp_ws[blk] = 1.0f / fmaxf(meanv, 1e-8f);
        }
    }

    cg::this_grid().sync();

    // ================= Phase 3: 1024 points/block =================
    if (tid < 16) rcp_lds[tid] = rcp_ws[(blk >> 6)*16 + tid];
    __syncthreads();

    const int i0   = tid & 7;
    const int psub = tid >> 3;               // 0..31

    const float4* Y4 = (const float4*)Y;
    float yr0[20], yr1[20];
#pragma unroll
    for (int q = 0; q < 5; ++q) {
        float4 t0 = Y4[i0*5 + q];
        float4 t1 = Y4[(i0+8)*5 + q];
        yr0[q*4+0]=t0.x; yr0[q*4+1]=t0.y; yr0[q*4+2]=t0.z; yr0[q*4+3]=t0.w;
        yr1[q*4+0]=t1.x; yr1[q*4+1]=t1.y; yr1[q*4+2]=t1.z; yr1[q*4+3]=t1.w;
    }
    const int l0 = (i0 == 0) ? 0 : ((i0 < 4) ? 1 : 2);
    const int l1 = (i0 == 0) ? 2 : 3;
    const float r00=rcp_lds[l0*4+0], r01=rcp_lds[l0*4+1], r02=rcp_lds[l0*4+2], r03=rcp_lds[l0*4+3];
    const float r10=rcp_lds[l1*4+0], r11=rcp_lds[l1*4+1], r12=rcp_lds[l1*4+2], r13=rcp_lds[l1*4+3];

#pragma unroll 1
    for (int it2 = 0; it2 < 32; ++it2) {
        const size_t pt = (size_t)blk*1024 + it2*32 + psub;
        const float* pp = patches + pt*3;
        float x = pp[0], y = pp[1], z = pp[2];
        float dist = sqrtf(x*x + y*y + z*z);
        float inv  = 1.0f / fmaxf(dist, 1e-6f);
        float nx = -x*inv, ny = -y*inv, nz = -z*inv;
        float m[20];
        compute_monoms(nx, ny, nz, m);
        float sl[4];
        compute_shells(dist, sl);

        float sh0 = 0.f, sh1 = 0.f;
#pragma unroll
        for (int j = 0; j < 20; ++j) {
            sh0 = fmaf(yr0[j], m[j], sh0);
            sh1 = fmaf(yr1[j], m[j], sh1);
        }
        f32x4 o0, o1;
        o0.x = sh0*sl[0]*r00;  o1.x = sh1*sl[0]*r10;
        o0.y = sh0*sl[1]*r01;  o1.y = sh1*sl[1]*r11;
        o0.z = sh0*sl[2]*r02;  o1.z = sh1*sl[2]*r12;
        o0.w = sh0*sl[3]*r03;  o1.w = sh1*sl[3]*r13;
        __builtin_nontemporal_store(o0, &out[pt*16 + i0]);
        __builtin_nontemporal_store(o1, &out[pt*16 + i0 + 8]);
    }
}

// ===================== Fallback trio (exact round-3 structure, 51.4 us) =====================
__global__ __launch_bounds__(256) void sh_pass1(const float* __restrict__ patches,
                                                const float* __restrict__ Y,
                                                float* __restrict__ ml_ws) {
    __shared__ float sh2_lds[8][32][17];
    __shared__ float shl2_lds[8][32][5];
    __shared__ float l2_lds[8][16][4];

    const int tid  = threadIdx.x;
    const int wv   = tid >> 6;
    const int lane = tid & 63;
    const int half = lane >> 5;
    const int p    = lane & 31;
    const int u    = wv * 2 + half;
    const int unit = blockIdx.x * 8 + u;

    const float* pp = patches + ((size_t)unit * 32 + p) * 3;
    float x = pp[0], y = pp[1], z = pp[2];
    float dist = sqrtf(x*x + y*y + z*z);
    float inv  = 1.0f / fmaxf(dist, 1e-6f);
    float nx = -x*inv, ny = -y*inv, nz = -z*inv;
    float m[20];
    compute_monoms(nx, ny, nz, m);

#pragma unroll
    for (int i = 0; i < 16; ++i) {
        float acc = 0.f;
#pragma unroll
        for (int j = 0; j < 20; ++j)
            acc = fmaf(Y[i*20 + j], m[j], acc);
        sh2_lds[u][p][i] = acc * acc;
    }
    float sl[4];
    compute_shells(dist, sl);
#pragma unroll
    for (int s = 0; s < 4; ++s) shl2_lds[u][p][s] = sl[s]*sl[s];
    __syncthreads();

    const int ri = lane >> 2, rs = lane & 3;
    const int u0 = wv*2, u1 = wv*2 + 1;
    float acc0 = 0.f, acc1 = 0.f;
#pragma unroll
    for (int q = 0; q < 32; ++q) {
        acc0 = fmaf(sh2_lds[u0][q][ri], shl2_lds[u0][q][rs], acc0);
        acc1 = fmaf(sh2_lds[u1][q][ri], shl2_lds[u1][q][rs], acc1);
    }
    l2_lds[u0][ri][rs] = acc0;
    l2_lds[u1][ri][rs] = acc1;
    __syncthreads();

    if (lane < 32) {
        const int h2 = lane >> 4;
        const int c  = lane & 15;
        const int l  = c >> 2, s = c & 3;
        const int uu = wv*2 + h2;
        const int start = l*l, cnt = 2*l + 1;
        float acc = 0.f;
        for (int t = 0; t < cnt; ++t) acc += l2_lds[uu][start + t][s];
        const int gu = blockIdx.x*8 + uu;
        ml_ws[(size_t)gu*16 + c] = sqrtf(acc);
    }
}

__global__ __launch_bounds__(256) void sh_pass2(const float* __restrict__ ml_ws,
                                                float* __restrict__ rcp_ws) {
    __shared__ float red2[256];
    const int b = blockIdx.x >> 4;
    const int c = blockIdx.x & 15;
    float acc = 0.f;
    for (int v = threadIdx.x; v < 2048; v += 256)
        acc += ml_ws[((size_t)(b*2048 + v))*16 + c];
    red2[threadIdx.x] = acc;
    __syncthreads();
    for (int st = 128; st > 0; st >>= 1) {
        if (threadIdx.x < st) red2[threadIdx.x] += red2[threadIdx.x + st];
        __syncthreads();
    }
    if (threadIdx.x == 0) {
        float meanv = red2[0] * (1.0f/2048.0f);
        rcp_ws[blockIdx.x] = 1.0f / fmaxf(meanv, 1e-8f);
    }
}

__global__ __launch_bounds__(256) void sh_pass3(const float* __restrict__ patches,
                                                const float* __restrict__ Y,
                                                const float* __restrict__ rcp_ws,
                                                f32x4* __restrict__ out) {
    const size_t g  = (size_t)blockIdx.x * 256 + threadIdx.x;
    const int    i0 = (int)(g & 7);
    const size_t pt = g >> 3;
    const int    b  = (int)(pt >> 16);

    const float* pp = patches + pt * 3;
    float x = pp[0], y = pp[1], z = pp[2];
    float dist = sqrtf(x*x + y*y + z*z);
    float inv  = 1.0f / fmaxf(dist, 1e-6f);
    float nx = -x*inv, ny = -y*inv, nz = -z*inv;
    float m[20];
    compute_monoms(nx, ny, nz, m);

    float sl[4];
    compute_shells(dist, sl);

    const float4* Y4 = (const float4*)Y;
    float sh0 = 0.f, sh1 = 0.f;
    {
        float yr0[20], yr1[20];
#pragma unroll
        for (int q = 0; q < 5; ++q) {
            float4 t0 = Y4[i0*5 + q];
            float4 t1 = Y4[(i0+8)*5 + q];
            yr0[q*4+0]=t0.x; yr0[q*4+1]=t0.y; yr0[q*4+2]=t0.z; yr0[q*4+3]=t0.w;
            yr1[q*4+0]=t1.x; yr1[q*4+1]=t1.y; yr1[q*4+2]=t1.z; yr1[q*4+3]=t1.w;
        }
#pragma unroll
        for (int j = 0; j < 20; ++j) {
            sh0 = fmaf(yr0[j], m[j], sh0);
            sh1 = fmaf(yr1[j], m[j], sh1);
        }
    }

    const int l0 = (i0 == 0) ? 0 : ((i0 < 4) ? 1 : 2);
    const int l1 = (i0 == 0) ? 2 : 3;
    const float4 r0 = ((const float4*)rcp_ws)[b*4 + l0];
    const float4 r1 = ((const float4*)rcp_ws)[b*4 + l1];

    f32x4 o0, o1;
    o0.x = sh0 * sl[0] * r0.x;  o1.x = sh1 * sl[0] * r1.x;
    o0.y = sh0 * sl[1] * r0.y;  o1.y = sh1 * sl[1] * r1.y;
    o0.z = sh0 * sl[2] * r0.z;  o1.z = sh1 * sl[2] * r1.z;
    o0.w = sh0 * sl[3] * r0.w;  o1.w = sh1 * sl[3] * r1.w;

    __builtin_nontemporal_store(o0, &out[pt*16 + i0]);
    __builtin_nontemporal_store(o1, &out[pt*16 + i0 + 8]);
}

extern "C" void kernel_launch(void* const* d_in, const int* in_sizes, int n_in,
                              void* d_out, int out_size, void* d_ws, size_t ws_size,
                              hipStream_t stream) {
    const float* patches = (const float*)d_in[0];   // 8*2048*32*3
    const float* Y       = (const float*)d_in[1];   // 16*20
    f32x4* out4 = (f32x4*)d_out;

    float* partials = (float*)d_ws;                 // 512*16
    float* rcp_ws   = partials + 512*16;            // 128
    float* ml_ws    = rcp_ws + 128;                 // 16384*16 (fallback)
    float* rcp2_ws  = ml_ws + 16384*16;             // 128 (fallback)

    void* args[] = { (void*)&patches, (void*)&Y, (void*)&partials,
                     (void*)&rcp_ws, (void*)&out4 };
    hipError_t err = hipLaunchCooperativeKernel((void*)sh_fused, dim3(512), dim3(256),
                                                args, 0, stream);
    if (err != hipSuccess) {
        // deterministic fallback: proven 3-kernel path
        sh_pass1<<<2048, 256, 0, stream>>>(patches, Y, ml_ws);
        sh_pass2<<<128, 256, 0, stream>>>(ml_ws, rcp2_ws);
        sh_pass3<<<16384, 256, 0, stream>>>(patches, Y, rcp2_ws, out4);
    }
}

// Round 8
// 82.966 us; speedup vs baseline: 1.6910x; 1.6910x over previous
//
#include <hip/hip_runtime.h>

typedef float f32x4 __attribute__((ext_vector_type(4)));

// out[b][v][p][i][s] = shell[s]*sh[i] / norm[b][l(i)][s]
// B=8 V=2048 P=32 I=16 S=4, monoms=20
// DIAGNOSTIC ROUND: exact round-3 trio + duplicated pass3 node (idempotent).
// Delta vs 51.4us isolates pass3's true duration.

__device__ __forceinline__ void compute_monoms(float nx, float ny, float nz, float* m) {
    float zp2 = nz*nz, zp3 = zp2*nz;
    float yp2 = ny*ny, yp3 = yp2*ny;
    float xp2 = nx*nx, xp3 = xp2*nx;
    m[0]=1.0f;  m[1]=nz;       m[2]=zp2;      m[3]=zp3;
    m[4]=ny;    m[5]=ny*nz;    m[6]=ny*zp2;
    m[7]=yp2;   m[8]=yp2*nz;   m[9]=yp3;
    m[10]=nx;   m[11]=nx*nz;   m[12]=nx*zp2;
    m[13]=nx*ny; m[14]=nx*ny*nz; m[15]=nx*yp2;
    m[16]=xp2;  m[17]=xp2*nz;  m[18]=xp2*ny;
    m[19]=xp3;
}

__device__ __forceinline__ void compute_shells(float dist, float* sl) {
    const float B1 = 32.0f/3.0f, B2 = 64.0f/3.0f, B3 = 32.0f;
    const float C1 = -16.0f/9.0f, C2 = -64.0f/9.0f, C3 = -16.0f;
    float nd2 = -16.0f * dist * dist;
    sl[0] = __expf(nd2);
    sl[1] = __expf(fmaf(B1, dist, nd2 + C1));
    sl[2] = __expf(fmaf(B2, dist, nd2 + C2));
    sl[3] = __expf(fmaf(B3, dist, nd2 + C3));
    float den = sl[0] + sl[1] + sl[2] + sl[3];
    float r = 1.0f / fmaxf(den, 1e-6f);
    float mask = (dist <= 1.0f) ? r : 0.0f;
#pragma unroll
    for (int s = 0; s < 4; ++s) sl[s] *= mask;
}

__global__ __launch_bounds__(256) void sh_pass1(const float* __restrict__ patches,
                                                const float* __restrict__ Y,
                                                float* __restrict__ ml_ws) {
    __shared__ float sh2_lds[8][32][17];
    __shared__ float shl2_lds[8][32][5];
    __shared__ float l2_lds[8][16][4];

    const int tid  = threadIdx.x;
    const int wv   = tid >> 6;
    const int lane = tid & 63;
    const int half = lane >> 5;
    const int p    = lane & 31;
    const int u    = wv * 2 + half;
    const int unit = blockIdx.x * 8 + u;

    const float* pp = patches + ((size_t)unit * 32 + p) * 3;
    float x = pp[0], y = pp[1], z = pp[2];
    float dist = sqrtf(x*x + y*y + z*z);
    float inv  = 1.0f / fmaxf(dist, 1e-6f);
    float nx = -x*inv, ny = -y*inv, nz = -z*inv;
    float m[20];
    compute_monoms(nx, ny, nz, m);

#pragma unroll
    for (int i = 0; i < 16; ++i) {
        float acc = 0.f;
#pragma unroll
        for (int j = 0; j < 20; ++j)
            acc = fmaf(Y[i*20 + j], m[j], acc);
        sh2_lds[u][p][i] = acc * acc;
    }
    float sl[4];
    compute_shells(dist, sl);
#pragma unroll
    for (int s = 0; s < 4; ++s) shl2_lds[u][p][s] = sl[s]*sl[s];
    __syncthreads();

    const int ri = lane >> 2, rs = lane & 3;
    const int u0 = wv*2, u1 = wv*2 + 1;
    float acc0 = 0.f, acc1 = 0.f;
#pragma unroll
    for (int q = 0; q < 32; ++q) {
        acc0 = fmaf(sh2_lds[u0][q][ri], shl2_lds[u0][q][rs], acc0);
        acc1 = fmaf(sh2_lds[u1][q][ri], shl2_lds[u1][q][rs], acc1);
    }
    l2_lds[u0][ri][rs] = acc0;
    l2_lds[u1][ri][rs] = acc1;
    __syncthreads();

    if (lane < 32) {
        const int h2 = lane >> 4;
        const int c  = lane & 15;
        const int l  = c >> 2, s = c & 3;
        const int uu = wv*2 + h2;
        const int start = l*l, cnt = 2*l + 1;
        float acc = 0.f;
        for (int t = 0; t < cnt; ++t) acc += l2_lds[uu][start + t][s];
        const int gu = blockIdx.x*8 + uu;
        ml_ws[(size_t)gu*16 + c] = sqrtf(acc);
    }
}

__global__ __launch_bounds__(256) void sh_pass2(const float* __restrict__ ml_ws,
                                                float* __restrict__ rcp_ws) {
    __shared__ float red[256];
    const int b = blockIdx.x >> 4;
    const int c = blockIdx.x & 15;
    float acc = 0.f;
    for (int v = threadIdx.x; v < 2048; v += 256)
        acc += ml_ws[((size_t)(b*2048 + v))*16 + c];
    red[threadIdx.x] = acc;
    __syncthreads();
    for (int st = 128; st > 0; st >>= 1) {
        if (threadIdx.x < st) red[threadIdx.x] += red[threadIdx.x + st];
        __syncthreads();
    }
    if (threadIdx.x == 0) {
        float meanv = red[0] * (1.0f/2048.0f);
        rcp_ws[blockIdx.x] = 1.0f / fmaxf(meanv, 1e-8f);
    }
}

__global__ __launch_bounds__(256) void sh_pass3(const float* __restrict__ patches,
                                                const float* __restrict__ Y,
                                                const float* __restrict__ rcp_ws,
                                                f32x4* __restrict__ out) {
    const size_t g  = (size_t)blockIdx.x * 256 + threadIdx.x;
    const int    i0 = (int)(g & 7);
    const size_t pt = g >> 3;
    const int    b  = (int)(pt >> 16);

    const float* pp = patches + pt * 3;
    float x = pp[0], y = pp[1], z = pp[2];
    float dist = sqrtf(x*x + y*y + z*z);
    float inv  = 1.0f / fmaxf(dist, 1e-6f);
    float nx = -x*inv, ny = -y*inv, nz = -z*inv;
    float m[20];
    compute_monoms(nx, ny, nz, m);

    float sl[4];
    compute_shells(dist, sl);

    const float4* Y4 = (const float4*)Y;
    float sh0 = 0.f, sh1 = 0.f;
    {
        float yr0[20], yr1[20];
#pragma unroll
        for (int q = 0; q < 5; ++q) {
            float4 t0 = Y4[i0*5 + q];
            float4 t1 = Y4[(i0+8)*5 + q];
            yr0[q*4+0]=t0.x; yr0[q*4+1]=t0.y; yr0[q*4+2]=t0.z; yr0[q*4+3]=t0.w;
            yr1[q*4+0]=t1.x; yr1[q*4+1]=t1.y; yr1[q*4+2]=t1.z; yr1[q*4+3]=t1.w;
        }
#pragma unroll
        for (int j = 0; j < 20; ++j) {
            sh0 = fmaf(yr0[j], m[j], sh0);
            sh1 = fmaf(yr1[j], m[j], sh1);
        }
    }

    const int l0 = (i0 == 0) ? 0 : ((i0 < 4) ? 1 : 2);
    const int l1 = (i0 == 0) ? 2 : 3;
    const float4 r0 = ((const float4*)rcp_ws)[b*4 + l0];
    const float4 r1 = ((const float4*)rcp_ws)[b*4 + l1];

    f32x4 o0, o1;
    o0.x = sh0 * sl[0] * r0.x;  o1.x = sh1 * sl[0] * r1.x;
    o0.y = sh0 * sl[1] * r0.y;  o1.y = sh1 * sl[1] * r1.y;
    o0.z = sh0 * sl[2] * r0.z;  o1.z = sh1 * sl[2] * r1.z;
    o0.w = sh0 * sl[3] * r0.w;  o1.w = sh1 * sl[3] * r1.w;

    __builtin_nontemporal_store(o0, &out[pt*16 + i0]);
    __builtin_nontemporal_store(o1, &out[pt*16 + i0 + 8]);
}

extern "C" void kernel_launch(void* const* d_in, const int* in_sizes, int n_in,
                              void* d_out, int out_size, void* d_ws, size_t ws_size,
                              hipStream_t stream) {
    const float* patches = (const float*)d_in[0];   // 8*2048*32*3
    const float* Y       = (const float*)d_in[1];   // 16*20
    float* out = (float*)d_out;                     // 8*2048*32*16*4

    float* ml_ws  = (float*)d_ws;                   // 16384*16 floats = 1 MB
    float* rcp_ws = ml_ws + 16384*16;               // 128 floats

    sh_pass1<<<2048, 256, 0, stream>>>(patches, Y, ml_ws);
    sh_pass2<<<128, 256, 0, stream>>>(ml_ws, rcp_ws);
    sh_pass3<<<16384, 256, 0, stream>>>(patches, Y, rcp_ws, (f32x4*)out);
    // duplicated node: identical work, identical output (idempotent).
    // total - 51.4us  ==  dur(pass3) + one node gap
    sh_pass3<<<16384, 256, 0, stream>>>(patches, Y, rcp_ws, (f32x4*)out);
}

// Round 9
// 51.749 us; speedup vs baseline: 2.7111x; 1.6032x over previous
//
#include <hip/hip_runtime.h>

typedef float f32x4 __attribute__((ext_vector_type(4)));

// out[b][v][p][i][s] = shell[s]*sh[i] / norm[b][l(i)][s]
// B=8 V=2048 P=32 I=16 S=4, monoms=20
// 2-node structure: K1 (512 blocks -> partials[512][16]), K3 (2048 blocks:
// per-block rcp reduction prologue + 256 points/block write loop).

__device__ __forceinline__ void compute_monoms(float nx, float ny, float nz, float* m) {
    float zp2 = nz*nz, zp3 = zp2*nz;
    float yp2 = ny*ny, yp3 = yp2*ny;
    float xp2 = nx*nx, xp3 = xp2*nx;
    m[0]=1.0f;  m[1]=nz;       m[2]=zp2;      m[3]=zp3;
    m[4]=ny;    m[5]=ny*nz;    m[6]=ny*zp2;
    m[7]=yp2;   m[8]=yp2*nz;   m[9]=yp3;
    m[10]=nx;   m[11]=nx*nz;   m[12]=nx*zp2;
    m[13]=nx*ny; m[14]=nx*ny*nz; m[15]=nx*yp2;
    m[16]=xp2;  m[17]=xp2*nz;  m[18]=xp2*ny;
    m[19]=xp3;
}

__device__ __forceinline__ void compute_shells(float dist, float* sl) {
    const float B1 = 32.0f/3.0f, B2 = 64.0f/3.0f, B3 = 32.0f;
    const float C1 = -16.0f/9.0f, C2 = -64.0f/9.0f, C3 = -16.0f;
    float nd2 = -16.0f * dist * dist;
    sl[0] = __expf(nd2);
    sl[1] = __expf(fmaf(B1, dist, nd2 + C1));
    sl[2] = __expf(fmaf(B2, dist, nd2 + C2));
    sl[3] = __expf(fmaf(B3, dist, nd2 + C3));
    float den = sl[0] + sl[1] + sl[2] + sl[3];
    float r = 1.0f / fmaxf(den, 1e-6f);
    float mask = (dist <= 1.0f) ? r : 0.0f;
#pragma unroll
    for (int s = 0; s < 4; ++s) sl[s] *= mask;
}

// ---------------- K1: 512 blocks, 32 units each -> partials[blk][16] ----------------
__global__ __launch_bounds__(256) void sh_k1(const float* __restrict__ patches,
                                             const float* __restrict__ Y,
                                             float* __restrict__ partials) {
    __shared__ float sh2_lds[8][32][17];
    __shared__ float shl2_lds[8][32][5];
    __shared__ float l2_lds[8][16][4];
    __shared__ float red[8][16];

    const int tid  = threadIdx.x;
    const int blk  = blockIdx.x;
    const int wv   = tid >> 6;
    const int lane = tid & 63;
    const int half = lane >> 5;
    const int p    = lane & 31;
    const int u    = wv*2 + half;            // local unit 0..7

    float bsum = 0.f;
#pragma unroll 1
    for (int it = 0; it < 4; ++it) {
        const int unit = blk*32 + it*8 + u;  // 64 blocks per batch
        const float* pp = patches + ((size_t)unit*32 + p)*3;
        float x = pp[0], y = pp[1], z = pp[2];
        float dist = sqrtf(x*x + y*y + z*z);
        float inv  = 1.0f / fmaxf(dist, 1e-6f);
        float nx = -x*inv, ny = -y*inv, nz = -z*inv;
        float m[20];
        compute_monoms(nx, ny, nz, m);
#pragma unroll
        for (int i = 0; i < 16; ++i) {
            float acc = 0.f;
#pragma unroll
            for (int j = 0; j < 20; ++j)
                acc = fmaf(Y[i*20 + j], m[j], acc);   // uniform -> s_load
            sh2_lds[u][p][i] = acc * acc;
        }
        float sl[4];
        compute_shells(dist, sl);
#pragma unroll
        for (int s = 0; s < 4; ++s) shl2_lds[u][p][s] = sl[s]*sl[s];
        __syncthreads();

        const int ri = lane >> 2, rs = lane & 3;
        const int u0 = wv*2, u1 = wv*2 + 1;
        float a0 = 0.f, a1 = 0.f;
#pragma unroll
        for (int q = 0; q < 32; ++q) {
            a0 = fmaf(sh2_lds[u0][q][ri], shl2_lds[u0][q][rs], a0);
            a1 = fmaf(sh2_lds[u1][q][ri], shl2_lds[u1][q][rs], a1);
        }
        l2_lds[u0][ri][rs] = a0;
        l2_lds[u1][ri][rs] = a1;
        __syncthreads();

        if (lane < 32) {
            const int h2 = lane >> 4;
            const int c  = lane & 15;        // c = l*4 + s
            const int l  = c >> 2, s = c & 3;
            const int uu = wv*2 + h2;
            const int start = l*l, cnt = 2*l + 1;
            float acc = 0.f;
            for (int t = 0; t < cnt; ++t) acc += l2_lds[uu][start + t][s];
            red[uu][c] = sqrtf(acc);
        }
        __syncthreads();
        if (tid < 16) {
            float s2 = 0.f;
#pragma unroll
            for (int uu = 0; uu < 8; ++uu) s2 += red[uu][tid];
            bsum += s2;
        }
        __syncthreads();
    }
    if (tid < 16) partials[blk*16 + tid] = bsum;
}

// ---------------- K3: prologue rcp-reduce (64 rows) + 256 points/block ----------------
__global__ __launch_bounds__(256) void sh_k3(const float* __restrict__ patches,
                                             const float* __restrict__ Y,
                                             const float* __restrict__ partials,
                                             f32x4* __restrict__ out) {
    __shared__ float pr[16][17];
    __shared__ float rcp_lds[16];

    const int tid = threadIdx.x;
    const int blk = blockIdx.x;           // 0..2047, 256 blocks per batch
    const int bb  = blk >> 8;             // batch

    // prologue: rcp[c] = 1/max(mean_v ml, 1e-8); batch has 64 partial rows
    {
        const int ch = tid & 15, r0 = tid >> 4;   // r0 0..15
        float a = 0.f;
#pragma unroll
        for (int r = 0; r < 4; ++r)
            a += partials[((size_t)bb*64 + r0 + r*16)*16 + ch];
        pr[r0][ch] = a;
    }
    __syncthreads();
    if (tid < 16) {
        float s = 0.f;
#pragma unroll
        for (int r = 0; r < 16; ++r) s += pr[r][tid];
        float meanv = s * (1.0f/2048.0f);
        rcp_lds[tid] = 1.0f / fmaxf(meanv, 1e-8f);
    }
    __syncthreads();

    const int i0   = tid & 7;
    const int psub = tid >> 3;            // 0..31

    // hoist Y rows + rcp out of the point loop
    const float4* Y4 = (const float4*)Y;
    float yr0[20], yr1[20];
#pragma unroll
    for (int q = 0; q < 5; ++q) {
        float4 t0 = Y4[i0*5 + q];
        float4 t1 = Y4[(i0+8)*5 + q];
        yr0[q*4+0]=t0.x; yr0[q*4+1]=t0.y; yr0[q*4+2]=t0.z; yr0[q*4+3]=t0.w;
        yr1[q*4+0]=t1.x; yr1[q*4+1]=t1.y; yr1[q*4+2]=t1.z; yr1[q*4+3]=t1.w;
    }
    const int l0 = (i0 == 0) ? 0 : ((i0 < 4) ? 1 : 2);
    const int l1 = (i0 == 0) ? 2 : 3;
    const float r00=rcp_lds[l0*4+0], r01=rcp_lds[l0*4+1], r02=rcp_lds[l0*4+2], r03=rcp_lds[l0*4+3];
    const float r10=rcp_lds[l1*4+0], r11=rcp_lds[l1*4+1], r12=rcp_lds[l1*4+2], r13=rcp_lds[l1*4+3];

#pragma unroll 1
    for (int it2 = 0; it2 < 8; ++it2) {
        const size_t pt = (size_t)blk*256 + it2*32 + psub;
        const float* pp = patches + pt*3;
        float x = pp[0], y = pp[1], z = pp[2];
        float dist = sqrtf(x*x + y*y + z*z);
        float inv  = 1.0f / fmaxf(dist, 1e-6f);
        float nx = -x*inv, ny = -y*inv, nz = -z*inv;
        float m[20];
        compute_monoms(nx, ny, nz, m);
        float sl[4];
        compute_shells(dist, sl);

        float sh0 = 0.f, sh1 = 0.f;
#pragma unroll
        for (int j = 0; j < 20; ++j) {
            sh0 = fmaf(yr0[j], m[j], sh0);
            sh1 = fmaf(yr1[j], m[j], sh1);
        }
        f32x4 o0, o1;
        o0.x = sh0*sl[0]*r00;  o1.x = sh1*sl[0]*r10;
        o0.y = sh0*sl[1]*r01;  o1.y = sh1*sl[1]*r11;
        o0.z = sh0*sl[2]*r02;  o1.z = sh1*sl[2]*r12;
        o0.w = sh0*sl[3]*r03;  o1.w = sh1*sl[3]*r13;
        __builtin_nontemporal_store(o0, &out[pt*16 + i0]);
        __builtin_nontemporal_store(o1, &out[pt*16 + i0 + 8]);
    }
}

extern "C" void kernel_launch(void* const* d_in, const int* in_sizes, int n_in,
                              void* d_out, int out_size, void* d_ws, size_t ws_size,
                              hipStream_t stream) {
    const float* patches = (const float*)d_in[0];   // 8*2048*32*3
    const float* Y       = (const float*)d_in[1];   // 16*20
    f32x4* out4 = (f32x4*)d_out;

    float* partials = (float*)d_ws;                 // 512*16 floats = 32 KB

    sh_k1<<<512, 256, 0, stream>>>(patches, Y, partials);
    sh_k3<<<2048, 256, 0, stream>>>(patches, Y, partials, out4);
}

// Round 10
// 42.799 us; speedup vs baseline: 3.2780x; 1.2091x over previous
//
#include <hip/hip_runtime.h>

typedef float f32x4 __attribute__((ext_vector_type(4)));

// out[b][v][p][i][s] = shell[s]*sh[i] / norm[b][l(i)][s]
// B=8 V=2048 P=32 I=16 S=4, monoms=20
// 2-node: k1 (2048 blk, 8 units -> partials[2048][16]),
//         k3 (2048 blk: rcp-reduce prologue + LDS point-staging + 256 points/block)

__device__ __forceinline__ void compute_monoms(float nx, float ny, float nz, float* m) {
    float zp2 = nz*nz, zp3 = zp2*nz;
    float yp2 = ny*ny, yp3 = yp2*ny;
    float xp2 = nx*nx, xp3 = xp2*nx;
    m[0]=1.0f;  m[1]=nz;       m[2]=zp2;      m[3]=zp3;
    m[4]=ny;    m[5]=ny*nz;    m[6]=ny*zp2;
    m[7]=yp2;   m[8]=yp2*nz;   m[9]=yp3;
    m[10]=nx;   m[11]=nx*nz;   m[12]=nx*zp2;
    m[13]=nx*ny; m[14]=nx*ny*nz; m[15]=nx*yp2;
    m[16]=xp2;  m[17]=xp2*nz;  m[18]=xp2*ny;
    m[19]=xp3;
}

__device__ __forceinline__ void compute_shells(float dist, float* sl) {
    const float B1 = 32.0f/3.0f, B2 = 64.0f/3.0f, B3 = 32.0f;
    const float C1 = -16.0f/9.0f, C2 = -64.0f/9.0f, C3 = -16.0f;
    float nd2 = -16.0f * dist * dist;
    sl[0] = __expf(nd2);
    sl[1] = __expf(fmaf(B1, dist, nd2 + C1));
    sl[2] = __expf(fmaf(B2, dist, nd2 + C2));
    sl[3] = __expf(fmaf(B3, dist, nd2 + C3));
    float den = sl[0] + sl[1] + sl[2] + sl[3];
    float r = 1.0f / fmaxf(den, 1e-6f);
    float mask = (dist <= 1.0f) ? r : 0.0f;
#pragma unroll
    for (int s = 0; s < 4; ++s) sl[s] *= mask;
}

// ---------------- K1: 2048 blocks, 8 units -> block-sum -> partials[blk][16] ----------------
__global__ __launch_bounds__(256) void sh_k1(const float* __restrict__ patches,
                                             const float* __restrict__ Y,
                                             float* __restrict__ partials) {
    __shared__ float sh2_lds[8][32][17];
    __shared__ float shl2_lds[8][32][5];
    __shared__ float l2_lds[8][16][4];
    __shared__ float red[8][16];

    const int tid  = threadIdx.x;
    const int wv   = tid >> 6;
    const int lane = tid & 63;
    const int half = lane >> 5;
    const int p    = lane & 31;
    const int u    = wv * 2 + half;
    const int unit = blockIdx.x * 8 + u;

    const float* pp = patches + ((size_t)unit * 32 + p) * 3;
    float x = pp[0], y = pp[1], z = pp[2];
    float dist = sqrtf(x*x + y*y + z*z);
    float inv  = 1.0f / fmaxf(dist, 1e-6f);
    float nx = -x*inv, ny = -y*inv, nz = -z*inv;
    float m[20];
    compute_monoms(nx, ny, nz, m);

#pragma unroll
    for (int i = 0; i < 16; ++i) {
        float acc = 0.f;
#pragma unroll
        for (int j = 0; j < 20; ++j)
            acc = fmaf(Y[i*20 + j], m[j], acc);   // uniform -> s_load
        sh2_lds[u][p][i] = acc * acc;
    }
    float sl[4];
    compute_shells(dist, sl);
#pragma unroll
    for (int s = 0; s < 4; ++s) shl2_lds[u][p][s] = sl[s]*sl[s];
    __syncthreads();

    const int ri = lane >> 2, rs = lane & 3;
    const int u0 = wv*2, u1 = wv*2 + 1;
    float acc0 = 0.f, acc1 = 0.f;
#pragma unroll
    for (int q = 0; q < 32; ++q) {
        acc0 = fmaf(sh2_lds[u0][q][ri], shl2_lds[u0][q][rs], acc0);
        acc1 = fmaf(sh2_lds[u1][q][ri], shl2_lds[u1][q][rs], acc1);
    }
    l2_lds[u0][ri][rs] = acc0;
    l2_lds[u1][ri][rs] = acc1;
    __syncthreads();

    if (lane < 32) {
        const int h2 = lane >> 4;
        const int c  = lane & 15;            // c = l*4 + s
        const int l  = c >> 2, s = c & 3;
        const int uu = wv*2 + h2;
        const int start = l*l, cnt = 2*l + 1;
        float acc = 0.f;
        for (int t = 0; t < cnt; ++t) acc += l2_lds[uu][start + t][s];
        red[uu][c] = sqrtf(acc);
    }
    __syncthreads();
    if (tid < 16) {
        float s2 = 0.f;
#pragma unroll
        for (int uu = 0; uu < 8; ++uu) s2 += red[uu][tid];
        partials[blockIdx.x*16 + tid] = s2;   // deterministic, no atomics
    }
}

// ---------------- K3: prologue rcp + production (LDS stage) + 8 consumption groups --------
__global__ __launch_bounds__(256) void sh_k3(const float* __restrict__ patches,
                                             const float* __restrict__ Y,
                                             const float* __restrict__ partials,
                                             f32x4* __restrict__ out) {
    __shared__ float2 mon2[256][13];   // [0..9]=m pairs, [10..11]=shells, [12]=pad
    __shared__ float pr[16][17];
    __shared__ float rcp_lds[16];

    const int tid = threadIdx.x;
    const int blk = blockIdx.x;        // 0..2047, 256 blocks per batch
    const int bb  = blk >> 8;          // batch

    // ---- prologue: rcp[c] = 1/max(mean_v ml, 1e-8); batch = 256 partial rows ----
    {
        const int ch = tid & 15, r0 = tid >> 4;   // r0 0..15
        float a = 0.f;
#pragma unroll
        for (int r = 0; r < 16; ++r)
            a += partials[((size_t)bb*256 + r0 + r*16)*16 + ch];
        pr[r0][ch] = a;
    }
    __syncthreads();
    if (tid < 16) {
        float s = 0.f;
#pragma unroll
        for (int r = 0; r < 16; ++r) s += pr[r][tid];
        float meanv = s * (1.0f/2048.0f);
        rcp_lds[tid] = 1.0f / fmaxf(meanv, 1e-8f);
    }

    // ---- production: thread t computes point blk*256+t once -> LDS ----
    {
        const size_t ptg = (size_t)blk*256 + tid;
        const float* pp = patches + ptg*3;
        float x = pp[0], y = pp[1], z = pp[2];
        float dist = sqrtf(x*x + y*y + z*z);
        float inv  = 1.0f / fmaxf(dist, 1e-6f);
        float nx = -x*inv, ny = -y*inv, nz = -z*inv;
        float m[20];
        compute_monoms(nx, ny, nz, m);
        float sl[4];
        compute_shells(dist, sl);
#pragma unroll
        for (int k = 0; k < 10; ++k)
            mon2[tid][k] = make_float2(m[2*k], m[2*k+1]);
        mon2[tid][10] = make_float2(sl[0], sl[1]);
        mon2[tid][11] = make_float2(sl[2], sl[3]);
    }
    __syncthreads();

    // ---- consumption: thread (psub, i0) handles rows i0, i0+8 for 8 point-groups ----
    const int i0   = tid & 7;
    const int psub = tid >> 3;           // 0..31

    const float4* Y4 = (const float4*)Y;
    float yr0[20], yr1[20];
#pragma unroll
    for (int q = 0; q < 5; ++q) {
        float4 t0 = Y4[i0*5 + q];
        float4 t1 = Y4[(i0+8)*5 + q];
        yr0[q*4+0]=t0.x; yr0[q*4+1]=t0.y; yr0[q*4+2]=t0.z; yr0[q*4+3]=t0.w;
        yr1[q*4+0]=t1.x; yr1[q*4+1]=t1.y; yr1[q*4+2]=t1.z; yr1[q*4+3]=t1.w;
    }
    const int l0 = (i0 == 0) ? 0 : ((i0 < 4) ? 1 : 2);
    const int l1 = (i0 == 0) ? 2 : 3;
    const float r00=rcp_lds[l0*4+0], r01=rcp_lds[l0*4+1], r02=rcp_lds[l0*4+2], r03=rcp_lds[l0*4+3];
    const float r10=rcp_lds[l1*4+0], r11=rcp_lds[l1*4+1], r12=rcp_lds[l1*4+2], r13=rcp_lds[l1*4+3];

#pragma unroll 1
    for (int it2 = 0; it2 < 8; ++it2) {
        const int r = it2*32 + psub;               // staged point row
        float sh0 = 0.f, sh1 = 0.f;
#pragma unroll
        for (int k = 0; k < 10; ++k) {
            float2 mk = mon2[r][k];
            sh0 = fmaf(yr0[2*k], mk.x, sh0); sh0 = fmaf(yr0[2*k+1], mk.y, sh0);
            sh1 = fmaf(yr1[2*k], mk.x, sh1); sh1 = fmaf(yr1[2*k+1], mk.y, sh1);
        }
        float2 s01 = mon2[r][10];
        float2 s23 = mon2[r][11];

        const size_t pt = (size_t)blk*256 + r;
        f32x4 o0, o1;
        o0.x = sh0*s01.x*r00;  o1.x = sh1*s01.x*r10;
        o0.y = sh0*s01.y*r01;  o1.y = sh1*s01.y*r11;
        o0.z = sh0*s23.x*r02;  o1.z = sh1*s23.x*r12;
        o0.w = sh0*s23.y*r03;  o1.w = sh1*s23.y*r13;
        __builtin_nontemporal_store(o0, &out[pt*16 + i0]);
        __builtin_nontemporal_store(o1, &out[pt*16 + i0 + 8]);
    }
}

extern "C" void kernel_launch(void* const* d_in, const int* in_sizes, int n_in,
                              void* d_out, int out_size, void* d_ws, size_t ws_size,
                              hipStream_t stream) {
    const float* patches = (const float*)d_in[0];   // 8*2048*32*3
    const float* Y       = (const float*)d_in[1];   // 16*20
    f32x4* out4 = (f32x4*)d_out;

    float* partials = (float*)d_ws;                 // 2048*16 floats = 128 KB

    sh_k1<<<2048, 256, 0, stream>>>(patches, Y, partials);
    sh_k3<<<2048, 256, 0, stream>>>(patches, Y, partials, out4);
}